// Round 2
// baseline (72.725 us; speedup 1.0000x reference)
//
#include <hip/hip_runtime.h>
#include <hip/hip_bf16.h>
#include <stdint.h>

// Maj3FC: out[b,c] = 2.25 * sum_g sign( sum_{k<3} sign(x[b,3g+k])*sign(w[c,3g+k]) )
// B=512, C_IN=1536, C_OUT=512, G=512 groups of 3.
//
// Encoding: per row, two bitplanes P (v>0) and N (v<0). Each group of 3
// occupies one nibble (bits 0..2; bit 3 = 0). 8 groups/word -> 64 words/row.
// Exact integer math -> absmax 0 vs reference.
//
// R2: op-count cut (and_or / add3 / ge-count instead of NOT), ds_read_b128
// (stride 66 -> 16B aligned, 2-way bank alias = free), full unroll.

#define CIN   1536
#define B_DIM 512
#define COUT  512
#define WORDS 64   // 1536 elems / (8 groups * 3 elems per word)
#define STRIDE 66  // uint2 stride: even -> b128-alignable; 132 dwords % 32 = 4

// ---------------- pack kernel ----------------
// 256 blocks x 256 threads. Blocks 0..127 pack x (4 rows each),
// blocks 128..255 pack w. Coalesced float4 staging into LDS, then
// 1 thread per packed word (4 rows * 64 words = 256 threads).
__global__ __launch_bounds__(256) void pack_kernel(
    const float* __restrict__ x, const float* __restrict__ w,
    uint2* __restrict__ px, uint2* __restrict__ pw) {
  __shared__ float buf[4 * CIN];
  int bid = blockIdx.x;
  const float* src;
  uint2* dst;
  int row0;
  if (bid < 128) { src = x;  dst = px; row0 = bid * 4; }
  else           { src = w;  dst = pw; row0 = (bid - 128) * 4; }

  const float4* s4 = (const float4*)(src + (size_t)row0 * CIN);
  float4* b4 = (float4*)buf;
  #pragma unroll
  for (int i = threadIdx.x; i < 4 * CIN / 4; i += 256) b4[i] = s4[i];
  __syncthreads();

  int r  = threadIdx.x >> 6;   // 0..3 row within block
  int wd = threadIdx.x & 63;   // 0..63 word
  const float* rowp = buf + r * CIN + wd * 24;
  unsigned P = 0, N = 0;
  #pragma unroll
  for (int k = 0; k < 24; k++) {
    float v = rowp[k];
    unsigned bit = (unsigned)((k / 3) * 4 + (k % 3));
    P |= (v > 0.0f ? 1u : 0u) << bit;
    N |= (v < 0.0f ? 1u : 0u) << bit;
  }
  dst[(size_t)(row0 + r) * WORDS + wd] = make_uint2(P, N);
}

// ---------------- main kernel ----------------
// 16x16 output tile per block, 256 threads, 1 output each.
// grid = (32, 32) = 1024 blocks -> 4 blocks/CU, 16 waves/CU.
__device__ __forceinline__ void maj3_word(unsigned xp, unsigned xn,
                                          unsigned wp, unsigned wn,
                                          int& acc_gt, int& acc_ge) {
  const unsigned M1 = 0x11111111u, M8 = 0x88888888u;
  unsigned pos = (xp & wp) | (xn & wn);  // product == +1  (v_and + v_and_or)
  unsigned neg = (xp & wn) | (xn & wp);  // product == -1
  // per-nibble 3-bit popcounts (cp, cn in [0,3]); v_add3
  unsigned cp = (pos & M1) + ((pos >> 1) & M1) + ((pos >> 2) & M1);
  unsigned cn = (neg & M1) + ((neg >> 1) & M1) + ((neg >> 2) & M1);
  // u nibble = cp - cn + 8 in [5,11]; bit3 <=> cp >= cn
  unsigned u = (cp | M8) - cn;
  // t nibble = u - 1 in [4,10], no inter-nibble borrow; bit3 <=> cp > cn
  unsigned t = u - M1;
  acc_gt += __popc(t & M8);   // groups with sign +1
  acc_ge += __popc(u & M8);   // groups with sign >= 0
}

__global__ __launch_bounds__(256) void maj3_kernel(
    const uint2* __restrict__ px, const uint2* __restrict__ pw,
    float* __restrict__ out) {
  __shared__ __align__(16) uint2 sx[16][STRIDE];
  __shared__ __align__(16) uint2 sw[16][STRIDE];

  const int b0 = blockIdx.y * 16;
  const int c0 = blockIdx.x * 16;
  const int tid = threadIdx.x;

  // cooperative load: 16 rows x 64 words for each operand
  #pragma unroll
  for (int i = tid; i < 16 * WORDS; i += 256) {
    int r = i >> 6, wd = i & 63;
    sx[r][wd] = px[(size_t)(b0 + r) * WORDS + wd];
    sw[r][wd] = pw[(size_t)(c0 + r) * WORDS + wd];
  }
  __syncthreads();

  const int tx = tid & 15;   // c within tile
  const int ty = tid >> 4;   // b within tile

  int acc_gt = 0, acc_ge = 0;

  const uint4* xrow = (const uint4*)&sx[ty][0];  // 2 packed words per uint4
  const uint4* wrow = (const uint4*)&sw[tx][0];

  #pragma unroll
  for (int i = 0; i < WORDS / 2; i++) {
    uint4 xa = xrow[i];   // ds_read_b128: (P0,N0,P1,N1)
    uint4 wb = wrow[i];
    maj3_word(xa.x, xa.y, wb.x, wb.y, acc_gt, acc_ge);
    maj3_word(xa.z, xa.w, wb.z, wb.w, acc_gt, acc_ge);
  }

  // #lt = 512 - acc_ge  ->  sum(sign) = acc_gt - #lt = acc_gt + acc_ge - 512
  out[(size_t)(b0 + ty) * COUT + (c0 + tx)] =
      2.25f * (float)(acc_gt + acc_ge - 512);
}

extern "C" void kernel_launch(void* const* d_in, const int* in_sizes, int n_in,
                              void* d_out, int out_size, void* d_ws, size_t ws_size,
                              hipStream_t stream) {
  const float* x = (const float*)d_in[0];   // [512, 1536]
  const float* w = (const float*)d_in[1];   // [512, 1536]
  float* out = (float*)d_out;               // [512, 512]

  uint2* px = (uint2*)d_ws;                 // [512][64]  (256 KB)
  uint2* pw = px + (size_t)B_DIM * WORDS;   // [512][64]  (256 KB)

  pack_kernel<<<256, 256, 0, stream>>>(x, w, px, pw);

  dim3 grid(COUT / 16, B_DIM / 16);
  maj3_kernel<<<grid, 256, 0, stream>>>(px, pw, out);
}

// Round 3
// 71.601 us; speedup vs baseline: 1.0157x; 1.0157x over previous
//
#include <hip/hip_runtime.h>
#include <hip/hip_bf16.h>
#include <stdint.h>

// Maj3FC: out[b,c] = 2.25 * sum_g sign( sum_{k<3} sign(x[b,3g+k])*sign(w[c,3g+k]) )
// B=512, C_IN=1536, C_OUT=512, G=512 groups of 3. Exact integer math -> absmax 0.
//
// R3: 3-bit-field packing (10 groups / 30 elems per 32-bit word, element k of
// the word at bit k) -> 52 words/row instead of 64 (x0.81 VALU and LDS), plus
// 2-output register blocking sharing the w fragment (x0.75 LDS instrs).
// SWAR per-field compare: field value cp-cn+4 in [1,7], no inter-field borrow;
// bit2 of (cp|M4)-cn  <=> cp>=cn; bit2 of that minus M1 <=> cp>cn.

#define CIN    1536
#define B_DIM  512
#define COUT   512
#define WORDS3 52   // ceil(512 groups / 10 per word); word 51 holds 2 groups
#define WSTRIDE 54  // LDS row stride in uint2: 108 dwords % 32 = 12 -> 2-way max

// ---------------- pack kernel ----------------
// 256 blocks x 256 threads. Blocks 0..127 pack x (4 rows each), 128..255 pack
// w. Coalesced float4 staging into LDS, then 1 thread per packed word.
__global__ __launch_bounds__(256) void pack_kernel(
    const float* __restrict__ x, const float* __restrict__ w,
    uint2* __restrict__ px, uint2* __restrict__ pw) {
  __shared__ float buf[4 * CIN];
  int bid = blockIdx.x;
  const float* src;
  uint2* dst;
  int row0;
  if (bid < 128) { src = x;  dst = px; row0 = bid * 4; }
  else           { src = w;  dst = pw; row0 = (bid - 128) * 4; }

  const float4* s4 = (const float4*)(src + (size_t)row0 * CIN);
  float4* b4 = (float4*)buf;
  #pragma unroll
  for (int i = threadIdx.x; i < 4 * CIN / 4; i += 256) b4[i] = s4[i];
  __syncthreads();

  int r  = threadIdx.x >> 6;   // 0..3 row within block
  int wd = threadIdx.x & 63;   // 0..63; only 0..51 active
  if (wd < WORDS3) {
    const float* rowp = buf + r * CIN + wd * 30;
    int nmax = CIN - wd * 30;  // 30 for wd<51, 6 for wd==51
    unsigned P = 0, N = 0;
    #pragma unroll
    for (int k = 0; k < 30; k++) {
      if (k < nmax) {
        float v = rowp[k];
        P |= (v > 0.0f ? 1u : 0u) << k;
        N |= (v < 0.0f ? 1u : 0u) << k;
      }
    }
    dst[(size_t)(row0 + r) * WORDS3 + wd] = make_uint2(P, N);
  }
}

// ---------------- main kernel ----------------
__device__ __forceinline__ void maj3w(unsigned xp, unsigned xn,
                                      unsigned wp, unsigned wn,
                                      int& gt, int& ge) {
  const unsigned M1 = 0x09249249u;  // bit0 of each 3-bit field (10 fields)
  const unsigned M4 = 0x24924924u;  // bit2 of each field
  unsigned pos = (xp & wp) | (xn & wn);   // product == +1 per element
  unsigned neg = (xp & wn) | (xn & wp);   // product == -1
  unsigned cp = (pos & M1) + ((pos >> 1) & M1) + ((pos >> 2) & M1); // [0,3]
  unsigned cn = (neg & M1) + ((neg >> 1) & M1) + ((neg >> 2) & M1);
  unsigned u = (cp | M4) - cn;  // field = cp-cn+4 in [1,7]; bit2 <=> cp>=cn
  unsigned t = u - M1;          // field = cp-cn+3 in [0,6]; bit2 <=> cp>cn
  gt += __popc(t & M4);
  ge += __popc(u & M4);
}

// 32(b) x 16(c) tile, 256 threads, 2 outputs/thread (rows ty and ty+16 share
// the w fragment). grid = (32,16) = 512 blocks -> 2 blocks/CU, 8 waves/CU.
// LDS = (32+16)*54*8 = 20.7 KB.
__global__ __launch_bounds__(256) void maj3_kernel(
    const uint2* __restrict__ px, const uint2* __restrict__ pw,
    float* __restrict__ out) {
  __shared__ __align__(16) uint2 sx[32][WSTRIDE];
  __shared__ __align__(16) uint2 sw[16][WSTRIDE];

  const int b0 = blockIdx.y * 32;
  const int c0 = blockIdx.x * 16;
  const int tid = threadIdx.x;

  // Packed rows are dense in global: block's x region = 32*26 contiguous
  // uint4, w region = 16*26. Scatter into stride-27(uint4) LDS rows.
  const uint4* gx = (const uint4*)(px + (size_t)b0 * WORDS3);
  const uint4* gw = (const uint4*)(pw + (size_t)c0 * WORDS3);
  uint4* lx = (uint4*)sx;  // row stride 27 uint4
  uint4* lw = (uint4*)sw;
  #pragma unroll
  for (int i = tid; i < 32 * 26; i += 256) {
    int r = i / 26, wd = i - r * 26;
    lx[r * 27 + wd] = gx[i];
  }
  #pragma unroll
  for (int i = tid; i < 16 * 26; i += 256) {
    int r = i / 26, wd = i - r * 26;
    lw[r * 27 + wd] = gw[i];
  }
  __syncthreads();

  const int tx = tid & 15;   // c within tile
  const int ty = tid >> 4;   // b within tile (0..15); rows ty and ty+16

  int gt0 = 0, ge0 = 0, gt1 = 0, ge1 = 0;
  const uint4* x0 = (const uint4*)&sx[ty][0];
  const uint4* x1 = (const uint4*)&sx[ty + 16][0];
  const uint4* wr = (const uint4*)&sw[tx][0];

  #pragma unroll
  for (int i = 0; i < 26; i++) {
    uint4 a0 = x0[i];   // (P0,N0,P1,N1) = 2 packed words
    uint4 a1 = x1[i];
    uint4 b  = wr[i];
    maj3w(a0.x, a0.y, b.x, b.y, gt0, ge0);
    maj3w(a0.z, a0.w, b.z, b.w, gt0, ge0);
    maj3w(a1.x, a1.y, b.x, b.y, gt1, ge1);
    maj3w(a1.z, a1.w, b.z, b.w, gt1, ge1);
  }

  // 520 fields counted (512 real + 8 zero-padded; padded give gt=0,ge=1 and
  // cancel). sum(sign) = #gt - #lt = gt + ge - 520.
  out[(size_t)(b0 + ty) * COUT + (c0 + tx)] =
      2.25f * (float)(gt0 + ge0 - 520);
  out[(size_t)(b0 + ty + 16) * COUT + (c0 + tx)] =
      2.25f * (float)(gt1 + ge1 - 520);
}

extern "C" void kernel_launch(void* const* d_in, const int* in_sizes, int n_in,
                              void* d_out, int out_size, void* d_ws, size_t ws_size,
                              hipStream_t stream) {
  const float* x = (const float*)d_in[0];   // [512, 1536]
  const float* w = (const float*)d_in[1];   // [512, 1536]
  float* out = (float*)d_out;               // [512, 512]

  uint2* px = (uint2*)d_ws;                  // [512][52] (208 KB)
  uint2* pw = px + (size_t)B_DIM * WORDS3;   // [512][52]

  pack_kernel<<<256, 256, 0, stream>>>(x, w, px, pw);

  dim3 grid(COUT / 16, B_DIM / 32);
  maj3_kernel<<<grid, 256, 0, stream>>>(px, pw, out);
}